// Round 1
// baseline (698.350 us; speedup 1.0000x reference)
//
#include <hip/hip_runtime.h>
#include <hip/hip_bf16.h>

#define LN_EPS 1e-5f

__device__ __forceinline__ float wsum64(float v) {
    v += __shfl_xor(v, 1);
    v += __shfl_xor(v, 2);
    v += __shfl_xor(v, 4);
    v += __shfl_xor(v, 8);
    v += __shfl_xor(v, 16);
    v += __shfl_xor(v, 32);
    return v;
}

// ---------------- Kernel A: hv = LN(GELU(X @ W_node)) ----------------
// One wave per row (grid-stride). Lane c holds W[:,c] in 128 VGPRs.
__global__ __launch_bounds__(256) void node_proj_kernel(
    const float* __restrict__ X, const float* __restrict__ W,
    const float* __restrict__ g, const float* __restrict__ b,
    float* __restrict__ out, int nrows)
{
    __shared__ float xbuf[4][128];
    const int lane  = threadIdx.x & 63;
    const int wslot = threadIdx.x >> 6;
    const int gwave = (int)((blockIdx.x * blockDim.x + threadIdx.x) >> 6);
    const int nwave = (int)((gridDim.x * blockDim.x) >> 6);

    float w[128];
#pragma unroll
    for (int k = 0; k < 128; ++k) w[k] = W[k * 64 + lane];
    const float gg = g[lane], bb = b[lane];

    for (int r = gwave; r < nrows; r += nwave) {
        const float2 xv = *(const float2*)(X + (size_t)r * 128 + lane * 2);
        *(float2*)&xbuf[wslot][lane * 2] = xv;
        float a0 = 0.f, a1 = 0.f, a2 = 0.f, a3 = 0.f;
#pragma unroll
        for (int k4 = 0; k4 < 32; ++k4) {
            const float4 xq = *(const float4*)&xbuf[wslot][k4 * 4];
            a0 = fmaf(xq.x, w[4 * k4 + 0], a0);
            a1 = fmaf(xq.y, w[4 * k4 + 1], a1);
            a2 = fmaf(xq.z, w[4 * k4 + 2], a2);
            a3 = fmaf(xq.w, w[4 * k4 + 3], a3);
        }
        float p = (a0 + a1) + (a2 + a3);
        // exact GELU (erf form, torch default)
        p = 0.5f * p * (1.0f + erff(p * 0.70710678118654752f));
        const float mean = wsum64(p) * (1.0f / 64.0f);
        const float dlt  = p - mean;
        const float var  = wsum64(dlt * dlt) * (1.0f / 64.0f);
        out[(size_t)r * 64 + lane] = dlt * rsqrtf(var + LN_EPS) * gg + bb;
    }
}

// ------- Kernel B: per edge e: he=exp(LN(EF[e]@W_edge)); h[dst] += hv[src]*he -------
__global__ __launch_bounds__(256) void edge_kernel(
    const float* __restrict__ EF, const float* __restrict__ W,
    const float* __restrict__ g, const float* __restrict__ b,
    const int* __restrict__ src, const int* __restrict__ dst,
    const float* __restrict__ hv, float* __restrict__ h, int nedges)
{
    __shared__ float xbuf[4][128];
    const int lane  = threadIdx.x & 63;
    const int wslot = threadIdx.x >> 6;
    const int gwave = (int)((blockIdx.x * blockDim.x + threadIdx.x) >> 6);
    const int nwave = (int)((gridDim.x * blockDim.x) >> 6);

    float w[128];
#pragma unroll
    for (int k = 0; k < 128; ++k) w[k] = W[k * 64 + lane];
    const float gg = g[lane], bb = b[lane];

    int e = gwave;
    if (e >= nedges) return;
    float2 xreg = *(const float2*)(EF + (size_t)e * 128 + lane * 2);

    while (e < nedges) {
        const int s = src[e];
        const int d = dst[e];
        const float hvv = hv[(size_t)s * 64 + lane];   // 256B coalesced gather

        *(float2*)&xbuf[wslot][lane * 2] = xreg;
        const int en = e + nwave;
        if (en < nedges)
            xreg = *(const float2*)(EF + (size_t)en * 128 + lane * 2);  // prefetch

        float a0 = 0.f, a1 = 0.f, a2 = 0.f, a3 = 0.f;
#pragma unroll
        for (int k4 = 0; k4 < 32; ++k4) {
            const float4 xq = *(const float4*)&xbuf[wslot][k4 * 4];
            a0 = fmaf(xq.x, w[4 * k4 + 0], a0);
            a1 = fmaf(xq.y, w[4 * k4 + 1], a1);
            a2 = fmaf(xq.z, w[4 * k4 + 2], a2);
            a3 = fmaf(xq.w, w[4 * k4 + 3], a3);
        }
        float p = (a0 + a1) + (a2 + a3);
        const float mean = wsum64(p) * (1.0f / 64.0f);
        const float dlt  = p - mean;
        const float var  = wsum64(dlt * dlt) * (1.0f / 64.0f);
        const float y = __expf(dlt * rsqrtf(var + LN_EPS) * gg + bb);

        atomicAdd(h + (size_t)d * 64 + lane, y * hvv);
        e = en;
    }
}

// ---------------- Kernel C: out = LN(GELU(H @ W_out)) ----------------
// One wave per row; lane c computes cols c and c+64 (W_out[:,c] in 2x64 VGPRs).
__global__ __launch_bounds__(256) void out_proj_kernel(
    const float* __restrict__ Hin, const float* __restrict__ W,
    const float* __restrict__ g, const float* __restrict__ b,
    float* __restrict__ out, int nrows)
{
    __shared__ float xbuf[4][64];
    const int lane  = threadIdx.x & 63;
    const int wslot = threadIdx.x >> 6;
    const int gwave = (int)((blockIdx.x * blockDim.x + threadIdx.x) >> 6);
    const int nwave = (int)((gridDim.x * blockDim.x) >> 6);

    float w0[64], w1[64];
#pragma unroll
    for (int k = 0; k < 64; ++k) {
        w0[k] = W[k * 128 + lane];
        w1[k] = W[k * 128 + 64 + lane];
    }
    const float g0 = g[lane], b0 = b[lane];
    const float g1 = g[64 + lane], b1 = b[64 + lane];

    for (int r = gwave; r < nrows; r += nwave) {
        xbuf[wslot][lane] = Hin[(size_t)r * 64 + lane];
        float a0 = 0.f, a1 = 0.f, a2 = 0.f, a3 = 0.f;
        float c0 = 0.f, c1 = 0.f, c2 = 0.f, c3 = 0.f;
#pragma unroll
        for (int k4 = 0; k4 < 16; ++k4) {
            const float4 xq = *(const float4*)&xbuf[wslot][k4 * 4];
            a0 = fmaf(xq.x, w0[4 * k4 + 0], a0);
            a1 = fmaf(xq.y, w0[4 * k4 + 1], a1);
            a2 = fmaf(xq.z, w0[4 * k4 + 2], a2);
            a3 = fmaf(xq.w, w0[4 * k4 + 3], a3);
            c0 = fmaf(xq.x, w1[4 * k4 + 0], c0);
            c1 = fmaf(xq.y, w1[4 * k4 + 1], c1);
            c2 = fmaf(xq.z, w1[4 * k4 + 2], c2);
            c3 = fmaf(xq.w, w1[4 * k4 + 3], c3);
        }
        float p0 = (a0 + a1) + (a2 + a3);
        float p1 = (c0 + c1) + (c2 + c3);
        p0 = 0.5f * p0 * (1.0f + erff(p0 * 0.70710678118654752f));
        p1 = 0.5f * p1 * (1.0f + erff(p1 * 0.70710678118654752f));
        const float mean = wsum64(p0 + p1) * (1.0f / 128.0f);
        const float d0 = p0 - mean, d1 = p1 - mean;
        const float var = wsum64(d0 * d0 + d1 * d1) * (1.0f / 128.0f);
        const float inv = rsqrtf(var + LN_EPS);
        out[(size_t)r * 128 + lane]      = d0 * inv * g0 + b0;
        out[(size_t)r * 128 + 64 + lane] = d1 * inv * g1 + b1;
    }
}

extern "C" void kernel_launch(void* const* d_in, const int* in_sizes, int n_in,
                              void* d_out, int out_size, void* d_ws, size_t ws_size,
                              hipStream_t stream) {
    const float* node_feats = (const float*)d_in[0];
    const float* edge_feats = (const float*)d_in[1];
    const int*   src        = (const int*)d_in[2];
    const int*   dst        = (const int*)d_in[3];
    const float* W_node     = (const float*)d_in[4];
    const float* ln_ng      = (const float*)d_in[5];
    const float* ln_nb      = (const float*)d_in[6];
    const float* W_edge     = (const float*)d_in[7];
    const float* ln_eg      = (const float*)d_in[8];
    const float* ln_eb      = (const float*)d_in[9];
    const float* W_out      = (const float*)d_in[10];
    const float* ln_og      = (const float*)d_in[11];
    const float* ln_ob      = (const float*)d_in[12];
    float* out = (float*)d_out;

    const int N = in_sizes[0] / 128;
    const int E = in_sizes[2];

    float* hv = (float*)d_ws;                  // N*64 floats
    float* h  = hv + (size_t)N * 64;           // N*64 floats

    hipMemsetAsync(h, 0, (size_t)N * 64 * sizeof(float), stream);
    node_proj_kernel<<<640, 256, 0, stream>>>(node_feats, W_node, ln_ng, ln_nb, hv, N);
    edge_kernel<<<2048, 256, 0, stream>>>(edge_feats, W_edge, ln_eg, ln_eb, src, dst, hv, h, E);
    out_proj_kernel<<<640, 256, 0, stream>>>(h, W_out, ln_og, ln_ob, out, N);
}

// Round 2
// 368.160 us; speedup vs baseline: 1.8969x; 1.8969x over previous
//
#include <hip/hip_runtime.h>
#include <hip/hip_bf16.h>

#define LN_EPS 1e-5f

typedef __attribute__((ext_vector_type(8))) short short8_t;
typedef __attribute__((ext_vector_type(4))) float float4_t;

__device__ __forceinline__ float wsum64(float v) {
    v += __shfl_xor(v, 1);
    v += __shfl_xor(v, 2);
    v += __shfl_xor(v, 4);
    v += __shfl_xor(v, 8);
    v += __shfl_xor(v, 16);
    v += __shfl_xor(v, 32);
    return v;
}

__device__ __forceinline__ unsigned short f2bf(float x) {
    unsigned u = __builtin_bit_cast(unsigned, x);
    unsigned r = (u + 0x7FFFu + ((u >> 16) & 1u)) >> 16;
    return (unsigned short)r;
}

// ---------------- Kernel A: hv = LN(GELU(X @ W_node)) ---------------- (unchanged)
__global__ __launch_bounds__(256) void node_proj_kernel(
    const float* __restrict__ X, const float* __restrict__ W,
    const float* __restrict__ g, const float* __restrict__ b,
    float* __restrict__ out, int nrows)
{
    __shared__ float xbuf[4][128];
    const int lane  = threadIdx.x & 63;
    const int wslot = threadIdx.x >> 6;
    const int gwave = (int)((blockIdx.x * blockDim.x + threadIdx.x) >> 6);
    const int nwave = (int)((gridDim.x * blockDim.x) >> 6);

    float w[128];
#pragma unroll
    for (int k = 0; k < 128; ++k) w[k] = W[k * 64 + lane];
    const float gg = g[lane], bb = b[lane];

    for (int r = gwave; r < nrows; r += nwave) {
        const float2 xv = *(const float2*)(X + (size_t)r * 128 + lane * 2);
        *(float2*)&xbuf[wslot][lane * 2] = xv;
        float a0 = 0.f, a1 = 0.f, a2 = 0.f, a3 = 0.f;
#pragma unroll
        for (int k4 = 0; k4 < 32; ++k4) {
            const float4 xq = *(const float4*)&xbuf[wslot][k4 * 4];
            a0 = fmaf(xq.x, w[4 * k4 + 0], a0);
            a1 = fmaf(xq.y, w[4 * k4 + 1], a1);
            a2 = fmaf(xq.z, w[4 * k4 + 2], a2);
            a3 = fmaf(xq.w, w[4 * k4 + 3], a3);
        }
        float p = (a0 + a1) + (a2 + a3);
        p = 0.5f * p * (1.0f + erff(p * 0.70710678118654752f));
        const float mean = wsum64(p) * (1.0f / 64.0f);
        const float dlt  = p - mean;
        const float var  = wsum64(dlt * dlt) * (1.0f / 64.0f);
        out[(size_t)r * 64 + lane] = dlt * rsqrtf(var + LN_EPS) * gg + bb;
    }
}

// ------- Kernel B (MFMA): per 64-edge tile:
//   he = exp(LN(EF_tile @ W_edge)); h[dst] += hv[src] * he
__global__ __launch_bounds__(256) void edge_mfma_kernel(
    const float* __restrict__ EF, const float* __restrict__ W,
    const float* __restrict__ g, const float* __restrict__ b,
    const int* __restrict__ src, const int* __restrict__ dst,
    const float* __restrict__ hv, float* __restrict__ h, int nedges)
{
    // LDS: A tile (64 edges x 128 k, bf16, swizzled), Wt (64 cols x 128 k, bf16, swizzled)
    __shared__ __align__(16) unsigned short Abuf[64 * 128];
    __shared__ __align__(16) unsigned short Wbuf[64 * 128];
    __shared__ int srcb[64];
    __shared__ int dstb[64];

    const int t    = threadIdx.x;
    const int lane = t & 63;
    const int wv   = t >> 6;      // wave id 0..3

    // ---- stage W^T into LDS (once per block): Wt[c][k], swizzle elem ^= (c&7)<<3
    {
        const int c  = t & 63;
        const int kb = (t >> 6) * 32;
#pragma unroll
        for (int kk = 0; kk < 32; kk += 8) {
            unsigned short tmp[8];
#pragma unroll
            for (int i = 0; i < 8; ++i)
                tmp[i] = f2bf(W[(size_t)(kb + kk + i) * 64 + c]);
            unsigned idx = (unsigned)(c * 128 + kb + kk) ^ (unsigned)((c & 7) << 3);
            *(uint4*)&Wbuf[idx] = *(const uint4*)tmp;
        }
    }

    // per-lane LN params for the 4 col-tiles (col = ct*16 + (lane&15))
    float gv[4], bv[4];
#pragma unroll
    for (int ct = 0; ct < 4; ++ct) {
        gv[ct] = g[ct * 16 + (lane & 15)];
        bv[ct] = b[ct * 16 + (lane & 15)];
    }

    const int ntiles = (nedges + 63) >> 6;
    __syncthreads();

    for (int tile = blockIdx.x; tile < ntiles; tile += gridDim.x) {
        const int e0 = tile * 64;

        // ---- stage A tile: EF[e0..e0+63][0..127] -> bf16 swizzled LDS
#pragma unroll
        for (int j = 0; j < 8; ++j) {
            const int f   = t + j * 256;        // float4 id within 64x32 float4 tile
            const int row = f >> 5;
            const int k   = (f & 31) * 4;
            float4 v;
            const int e = e0 + row;
            if (e < nedges) v = *(const float4*)(EF + (size_t)e * 128 + k);
            else            v = make_float4(0.f, 0.f, 0.f, 0.f);
            unsigned short pk[4] = { f2bf(v.x), f2bf(v.y), f2bf(v.z), f2bf(v.w) };
            unsigned idx = (unsigned)(row * 128 + k) ^ (unsigned)((row & 7) << 3);
            *(uint2*)&Abuf[idx] = *(const uint2*)pk;
        }
        if (t < 64) {
            const int e = e0 + t;
            srcb[t] = (e < nedges) ? src[e] : 0;
            dstb[t] = (e < nedges) ? dst[e] : 0;
        }
        __syncthreads();

        // ---- MFMA: wave wv computes rows 16*wv..16*wv+15, all 64 cols
        const int r  = 16 * wv + (lane & 15);
        const int ka = (lane >> 4) * 8;
        short8_t a[4];
#pragma unroll
        for (int kt = 0; kt < 4; ++kt) {
            unsigned idx = (unsigned)(r * 128 + kt * 32 + ka) ^ (unsigned)((r & 7) << 3);
            a[kt] = *(const short8_t*)&Abuf[idx];
        }
        float4_t acc[4];
#pragma unroll
        for (int ct = 0; ct < 4; ++ct) {
            acc[ct].x = 0.f; acc[ct].y = 0.f; acc[ct].z = 0.f; acc[ct].w = 0.f;
        }
#pragma unroll
        for (int ct = 0; ct < 4; ++ct) {
            const int c = ct * 16 + (lane & 15);
#pragma unroll
            for (int kt = 0; kt < 4; ++kt) {
                unsigned idx = (unsigned)(c * 128 + kt * 32 + ka) ^ (unsigned)((c & 7) << 3);
                short8_t bfr = *(const short8_t*)&Wbuf[idx];
                acc[ct] = __builtin_amdgcn_mfma_f32_16x16x32_bf16(a[kt], bfr, acc[ct], 0, 0, 0);
            }
        }

        // ---- LN over 64 cols per edge row, exp, gather-mul, atomic scatter
        // C layout: col = ct*16 + (lane&15), row(local16) = (lane>>4)*4 + j
#pragma unroll
        for (int j = 0; j < 4; ++j) {
            float s = acc[0][j] + acc[1][j] + acc[2][j] + acc[3][j];
            s += __shfl_xor(s, 1); s += __shfl_xor(s, 2);
            s += __shfl_xor(s, 4); s += __shfl_xor(s, 8);
            const float mean = s * (1.0f / 64.0f);
            float d0 = acc[0][j] - mean, d1 = acc[1][j] - mean;
            float d2 = acc[2][j] - mean, d3 = acc[3][j] - mean;
            float vs = d0 * d0 + d1 * d1 + d2 * d2 + d3 * d3;
            vs += __shfl_xor(vs, 1); vs += __shfl_xor(vs, 2);
            vs += __shfl_xor(vs, 4); vs += __shfl_xor(vs, 8);
            const float inv = rsqrtf(vs * (1.0f / 64.0f) + LN_EPS);

            const int rloc = 16 * wv + (lane >> 4) * 4 + j;
            const int e    = e0 + rloc;
            if (e < nedges) {
                const int sn = srcb[rloc];
                const int dn = dstb[rloc];
                const int cb = lane & 15;
                float dd[4] = { d0, d1, d2, d3 };
#pragma unroll
                for (int ct = 0; ct < 4; ++ct) {
                    const float he = __expf(dd[ct] * inv * gv[ct] + bv[ct]);
                    const float m  = he * hv[(size_t)sn * 64 + ct * 16 + cb];
                    atomicAdd(h + (size_t)dn * 64 + ct * 16 + cb, m);
                }
            }
        }
        __syncthreads();   // Abuf reused next tile
    }
}

// ---------------- Kernel C: out = LN(GELU(H @ W_out)) ---------------- (unchanged)
__global__ __launch_bounds__(256) void out_proj_kernel(
    const float* __restrict__ Hin, const float* __restrict__ W,
    const float* __restrict__ g, const float* __restrict__ b,
    float* __restrict__ out, int nrows)
{
    __shared__ float xbuf[4][64];
    const int lane  = threadIdx.x & 63;
    const int wslot = threadIdx.x >> 6;
    const int gwave = (int)((blockIdx.x * blockDim.x + threadIdx.x) >> 6);
    const int nwave = (int)((gridDim.x * blockDim.x) >> 6);

    float w0[64], w1[64];
#pragma unroll
    for (int k = 0; k < 64; ++k) {
        w0[k] = W[k * 128 + lane];
        w1[k] = W[k * 128 + 64 + lane];
    }
    const float g0 = g[lane], b0 = b[lane];
    const float g1 = g[64 + lane], b1 = b[64 + lane];

    for (int r = gwave; r < nrows; r += nwave) {
        xbuf[wslot][lane] = Hin[(size_t)r * 64 + lane];
        float a0 = 0.f, a1 = 0.f, a2 = 0.f, a3 = 0.f;
        float c0 = 0.f, c1 = 0.f, c2 = 0.f, c3 = 0.f;
#pragma unroll
        for (int k4 = 0; k4 < 16; ++k4) {
            const float4 xq = *(const float4*)&xbuf[wslot][k4 * 4];
            a0 = fmaf(xq.x, w0[4 * k4 + 0], a0);
            a1 = fmaf(xq.y, w0[4 * k4 + 1], a1);
            a2 = fmaf(xq.z, w0[4 * k4 + 2], a2);
            a3 = fmaf(xq.w, w0[4 * k4 + 3], a3);
            c0 = fmaf(xq.x, w1[4 * k4 + 0], c0);
            c1 = fmaf(xq.y, w1[4 * k4 + 1], c1);
            c2 = fmaf(xq.z, w1[4 * k4 + 2], c2);
            c3 = fmaf(xq.w, w1[4 * k4 + 3], c3);
        }
        float p0 = (a0 + a1) + (a2 + a3);
        float p1 = (c0 + c1) + (c2 + c3);
        p0 = 0.5f * p0 * (1.0f + erff(p0 * 0.70710678118654752f));
        p1 = 0.5f * p1 * (1.0f + erff(p1 * 0.70710678118654752f));
        const float mean = wsum64(p0 + p1) * (1.0f / 128.0f);
        const float d0 = p0 - mean, d1 = p1 - mean;
        const float var = wsum64(d0 * d0 + d1 * d1) * (1.0f / 128.0f);
        const float inv = rsqrtf(var + LN_EPS);
        out[(size_t)r * 128 + lane]      = d0 * inv * g0 + b0;
        out[(size_t)r * 128 + 64 + lane] = d1 * inv * g1 + b1;
    }
}

extern "C" void kernel_launch(void* const* d_in, const int* in_sizes, int n_in,
                              void* d_out, int out_size, void* d_ws, size_t ws_size,
                              hipStream_t stream) {
    const float* node_feats = (const float*)d_in[0];
    const float* edge_feats = (const float*)d_in[1];
    const int*   src        = (const int*)d_in[2];
    const int*   dst        = (const int*)d_in[3];
    const float* W_node     = (const float*)d_in[4];
    const float* ln_ng      = (const float*)d_in[5];
    const float* ln_nb      = (const float*)d_in[6];
    const float* W_edge     = (const float*)d_in[7];
    const float* ln_eg      = (const float*)d_in[8];
    const float* ln_eb      = (const float*)d_in[9];
    const float* W_out      = (const float*)d_in[10];
    const float* ln_og      = (const float*)d_in[11];
    const float* ln_ob      = (const float*)d_in[12];
    float* out = (float*)d_out;

    const int N = in_sizes[0] / 128;
    const int E = in_sizes[2];

    float* hv = (float*)d_ws;                  // N*64 floats
    float* h  = hv + (size_t)N * 64;           // N*64 floats

    hipMemsetAsync(h, 0, (size_t)N * 64 * sizeof(float), stream);
    node_proj_kernel<<<640, 256, 0, stream>>>(node_feats, W_node, ln_ng, ln_nb, hv, N);
    edge_mfma_kernel<<<2048, 256, 0, stream>>>(edge_feats, W_edge, ln_eg, ln_eb, src, dst, hv, h, E);
    out_proj_kernel<<<640, 256, 0, stream>>>(h, W_out, ln_og, ln_ob, out, N);
}